// Round 10
// baseline (170.396 us; speedup 1.0000x reference)
//
#include <hip/hip_runtime.h>
#include <hip/hip_bf16.h>

// CorrelationNetwork — single fused kernel for MI355X (gfx950), round 14.
// R13 post-mortem: full-unroll + sreg[8][2] = third catastrophic spill
// (WRITE 27.6MB of scratch). Law: (512,4) cap fits ~120 live VGPRs; no
// cross-iteration register arrays. Reverted.
// R12 cycle audit: tile loop is LDS-pipe-bound (~4096 b128/CU ~ 20us);
// half of it is W2 reads. R14: wave geometry 4m-quarters x 2row-halves
// (32 m-cols x 32 rows per wave) -> w2r[2][4]=32 regs fits: W2 lives in
// REGISTERS (gathered from global f32 + RNE after prepass barrier), W2s
// LDS eliminated. Tiles become 16 half-tiles (one i, 64 j each). Peak
// regs ~108 (vs 190 in spill cases), nothing carried across iterations.
// Barriers 11->6 (part batched x4, dbuf). LDS 68.3KB, 2 blocks/CU.
// Stage/prepass/arithmetic verbatim R12 -> bit-identical output.

typedef __bf16 bf16x8 __attribute__((ext_vector_type(8)));
typedef float f32x4 __attribute__((ext_vector_type(4)));

__device__ __forceinline__ unsigned rne16(float x) {
  unsigned u = __float_as_uint(x);
  u += 0x7fffu + ((u >> 16) & 1u);
  return u >> 16;
}
__device__ __forceinline__ __bf16 us_as_bf16(unsigned short s) {
  union { unsigned short s; __bf16 h; } cv; cv.s = s; return cv.h;
}

__global__ __launch_bounds__(512, 4) void fused_kernel(
    const float* __restrict__ af, const float* __restrict__ W1,
    const float* __restrict__ b1, const float* __restrict__ W2,
    const float* __restrict__ b2, const float* __restrict__ w3,
    const float* __restrict__ b3, const float* __restrict__ mw,
    float* __restrict__ out)
{
  __shared__ __align__(16) __bf16 flbuf[2 * 64 * 72];      // hi/lo, 18 KB
  __bf16* const flh = flbuf;
  __bf16* const fll = flbuf + 64 * 72;
  __shared__ __align__(16) float AjF[64 * 132];            // 33 KB, pad-132
  __shared__ __align__(16) float AiF[16 * 132];            // 8.25 KB
  __shared__ float b2s[128], w3s[128];
  __shared__ float part[2][4][4][64];                      // [buf][tt][q][j] 8 KB

  const int tid  = threadIdx.x;
  const int lane = tid & 63;
  const int wave = tid >> 6;            // 0..7
  const int c = lane & 15, g = lane >> 4;
  const int wm2 = wave & 3;             // m-quarter (32 w2 cols)
  const int wn2 = wave >> 2;            // row half (32 of 64 j's)

  const int blk = blockIdx.x;
  const int b   = blk >> 2;             // 0..127
  const int iq  = blk & 3;              // i-quarter
  const int i0  = iq << 4;              // 16 i's

  // ---- softmax of mixing weights (block 0, wave 0 only)
  if (blk == 0 && tid < 64) {
    float v = mw[tid];
    float m = v;
    for (int off = 32; off > 0; off >>= 1) m = fmaxf(m, __shfl_xor(m, off));
    float e = expf(v - m);
    float s = e;
    for (int off = 32; off > 0; off >>= 1) s += __shfl_xor(s, off);
    out[128 * 64 * 64 + tid] = e / s;
  }

  // ---- stage fl = af[b][0..63][0..63] split into bf16 hi/lo (pad-72 rows)
  {
    const float4* srcQ = (const float4*)(af + (b << 13));
#pragma unroll
    for (int p = 0; p < 2; ++p) {
      const int idx = (p << 9) + tid;            // 0..1023 float4s
      const int n = idx >> 4, e = idx & 15;
      const float4 v = srcQ[(n << 5) + e];
      const unsigned h0 = rne16(v.x), h1 = rne16(v.y),
                     h2 = rne16(v.z), h3 = rne16(v.w);
      const unsigned l0 = rne16(v.x - __uint_as_float(h0 << 16));
      const unsigned l1 = rne16(v.y - __uint_as_float(h1 << 16));
      const unsigned l2 = rne16(v.z - __uint_as_float(h2 << 16));
      const unsigned l3 = rne16(v.w - __uint_as_float(h3 << 16));
      uint2 ph; ph.x = h0 | (h1 << 16); ph.y = h2 | (h3 << 16);
      uint2 pl; pl.x = l0 | (l1 << 16); pl.y = l2 | (l3 << 16);
      *(uint2*)&flh[n * 72 + (e << 2)] = ph;
      *(uint2*)&fll[n * 72 + (e << 2)] = pl;
    }
    if (tid < 128) b2s[tid] = b2[tid];
    else if (tid < 256) w3s[tid - 128] = w3[tid - 128];
  }

  const float bias3 = b3[0];

  __syncthreads();                               // flh/fll, b2s/w3s ready

  // ---- MFMA prepass (VERBATIM R12): wave w = htile (16 h-cols).
  // bf16x3: ah*bh + ah*bl + al*bh. Aj rows -> AjF; Ai rows (iq*16+c) -> AiF,
  // C-init = b1.
  {
    const int w = wave;
    bf16x8 ajh[2], ajl[2], aih[2], ail[2];
#pragma unroll
    for (int kc = 0; kc < 2; ++kc) {
      const float* wpj = W1 + ((64 + (kc << 5) + (g << 3)) << 7) + (w << 4) + c;
      const float* wpi = W1 + (((kc << 5) + (g << 3)) << 7) + (w << 4) + c;
#pragma unroll
      for (int e = 0; e < 8; ++e) {
        const float vj = wpj[e << 7];
        const unsigned hj = rne16(vj);
        ajh[kc][e] = us_as_bf16((unsigned short)hj);
        ajl[kc][e] = us_as_bf16((unsigned short)rne16(vj - __uint_as_float(hj << 16)));
        const float vi = wpi[e << 7];
        const unsigned hi_ = rne16(vi);
        aih[kc][e] = us_as_bf16((unsigned short)hi_);
        ail[kc][e] = us_as_bf16((unsigned short)rne16(vi - __uint_as_float(hi_ << 16)));
      }
    }
#pragma unroll
    for (int rt = 0; rt < 4; ++rt) {
      const __bf16* bp = &flh[((rt << 4) + c) * 72 + (g << 3)];
      const __bf16* bq = &fll[((rt << 4) + c) * 72 + (g << 3)];
      f32x4 acc = {0.f, 0.f, 0.f, 0.f};
#pragma unroll
      for (int kc = 0; kc < 2; ++kc) {
        const bf16x8 bh = *(const bf16x8*)(bp + (kc << 5));
        const bf16x8 bl = *(const bf16x8*)(bq + (kc << 5));
        acc = __builtin_amdgcn_mfma_f32_16x16x32_bf16(ajh[kc], bh, acc, 0, 0, 0);
        acc = __builtin_amdgcn_mfma_f32_16x16x32_bf16(ajh[kc], bl, acc, 0, 0, 0);
        acc = __builtin_amdgcn_mfma_f32_16x16x32_bf16(ajl[kc], bh, acc, 0, 0, 0);
      }
      *(f32x4*)&AjF[((rt << 4) + c) * 132 + (w << 4) + (g << 2)] = acc;
    }
    {
      const __bf16* bp = &flh[((iq << 4) + c) * 72 + (g << 3)];
      const __bf16* bq = &fll[((iq << 4) + c) * 72 + (g << 3)];
      f32x4 acc = *(const f32x4*)(b1 + (w << 4) + (g << 2));
#pragma unroll
      for (int kc = 0; kc < 2; ++kc) {
        const bf16x8 bh = *(const bf16x8*)(bp + (kc << 5));
        const bf16x8 bl = *(const bf16x8*)(bq + (kc << 5));
        acc = __builtin_amdgcn_mfma_f32_16x16x32_bf16(aih[kc], bh, acc, 0, 0, 0);
        acc = __builtin_amdgcn_mfma_f32_16x16x32_bf16(aih[kc], bl, acc, 0, 0, 0);
        acc = __builtin_amdgcn_mfma_f32_16x16x32_bf16(ail[kc], bh, acc, 0, 0, 0);
      }
      *(f32x4*)&AiF[c * 132 + (w << 4) + (g << 2)] = acc;
    }
  }

  __syncthreads();                               // AjF/AiF ready

  // ---- W2 -> REGISTERS (no LDS): lane (c,g), frag element e:
  // m = wm2*32 + mt*16 + c, k = kt*32 + g*8 + e, value = RNE(W2[k][m]).
  bf16x8 w2r[2][4];
#pragma unroll
  for (int mt = 0; mt < 2; ++mt)
#pragma unroll
    for (int kt = 0; kt < 4; ++kt) {
      const int m = (wm2 << 5) + (mt << 4) + c;
      const float* wp = W2 + (((kt << 5) + (g << 3)) << 7) + m;
      bf16x8 v;
#pragma unroll
      for (int e = 0; e < 8; ++e)
        v[e] = us_as_bf16((unsigned short)rne16(wp[e << 7]));
      w2r[mt][kt] = v;
    }

  // ---- tile-invariant Aj fragments -> registers (j = wn2*32 + tn*16 + c)
  f32x4 ajr[4][2][2];
#pragma unroll
  for (int kt = 0; kt < 4; ++kt)
#pragma unroll
    for (int tn = 0; tn < 2; ++tn) {
      const int j = (wn2 << 5) + (tn << 4) + c;
      const float* ajb = &AjF[j * 132 + (g << 3) + (kt << 5)];
      ajr[kt][tn][0] = *(const f32x4*)(ajb);
      ajr[kt][tn][1] = *(const f32x4*)(ajb + 4);
    }
  // no barrier needed: w2r/ajr are registers; all LDS deps already synced

  // ---- 16 half-tiles (one i each, 64 j), in 4 batches of 4
  for (int bt = 0; bt < 4; ++bt) {
    for (int tt = 0; tt < 4; ++tt) {
      const int tp = (bt << 2) + tt;             // i-local 0..15
      const float* aib = &AiF[tp * 132 + (g << 3)];

      f32x4 acc[2][2];
#pragma unroll
      for (int mt = 0; mt < 2; ++mt) {
        const f32x4 bv = *(const f32x4*)&b2s[(wm2 << 5) + (mt << 4) + (g << 2)];
        acc[mt][0] = bv;
        acc[mt][1] = bv;
      }

#pragma unroll
      for (int kt = 0; kt < 4; ++kt) {
        const f32x4 a0 = *(const f32x4*)(aib + (kt << 5));
        const f32x4 a1 = *(const f32x4*)(aib + (kt << 5) + 4);
        bf16x8 hv[2];
#pragma unroll
        for (int tn = 0; tn < 2; ++tn) {
          const f32x4 h0  = a0 + ajr[kt][tn][0];
          const f32x4 h1v = a1 + ajr[kt][tn][1];
#pragma unroll
          for (int e = 0; e < 4; ++e) {
            hv[tn][e]     = (__bf16)fmaxf(h0[e], 0.f);
            hv[tn][e + 4] = (__bf16)fmaxf(h1v[e], 0.f);
          }
        }
#pragma unroll
        for (int mt = 0; mt < 2; ++mt)
#pragma unroll
          for (int tn = 0; tn < 2; ++tn)
            acc[mt][tn] = __builtin_amdgcn_mfma_f32_16x16x32_bf16(
                w2r[mt][kt], hv[tn], acc[mt][tn], 0, 0, 0);
      }

      float s0 = 0.f, s1 = 0.f;
#pragma unroll
      for (int mt = 0; mt < 2; ++mt) {
        const f32x4 wv3 = *(const f32x4*)&w3s[(wm2 << 5) + (mt << 4) + (g << 2)];
#pragma unroll
        for (int p = 0; p < 4; ++p) {
          s0 = fmaf(fmaxf(acc[mt][0][p], 0.f), wv3[p], s0);
          s1 = fmaf(fmaxf(acc[mt][1][p], 0.f), wv3[p], s1);
        }
      }
      s0 += __shfl_xor(s0, 16);
      s0 += __shfl_xor(s0, 32);
      s1 += __shfl_xor(s1, 16);
      s1 += __shfl_xor(s1, 32);

      if (g == 0) {                              // 16 lanes, conflict-free
        part[bt & 1][tt][wm2][(wn2 << 5) + c]      = s0;
        part[bt & 1][tt][wm2][(wn2 << 5) + 16 + c] = s1;
      }
    }

    __syncthreads();                             // batch's part ready

    // combine batch bt: 256 threads, 1 output each (4 tt x 64 j)
    if (tid < 256) {
      const int tt = tid >> 6, j = tid & 63;
      const float v = part[bt & 1][tt][0][j] + part[bt & 1][tt][1][j] +
                      part[bt & 1][tt][2][j] + part[bt & 1][tt][3][j] + bias3;
      out[(b << 12) + ((i0 + (bt << 2) + tt) << 6) + j] =
          1.f / (1.f + __expf(-v));
    }
    // next batch writes the other part buffer; the barrier at the end of
    // batch bt+1 orders this combine before batch bt+2 reuses buffer bt&1
  }
}

extern "C" void kernel_launch(void* const* d_in, const int* in_sizes, int n_in,
                              void* d_out, int out_size, void* d_ws,
                              size_t ws_size, hipStream_t stream)
{
  const float* af = (const float*)d_in[0];   // (128,64,128)
  const float* W1 = (const float*)d_in[1];   // (128,128)
  const float* b1 = (const float*)d_in[2];   // (128,)
  const float* W2 = (const float*)d_in[3];   // (128,128)
  const float* b2 = (const float*)d_in[4];   // (128,)
  const float* w3 = (const float*)d_in[5];   // (128,)
  const float* b3 = (const float*)d_in[6];   // (1,)
  const float* mw = (const float*)d_in[7];   // (64,)
  float* out = (float*)d_out;                // 524288 corr + 64 weights

  (void)d_ws; (void)ws_size;
  // one kernel: 512 blocks (2/CU), block = (b, i-quarter), 16 half-tiles
  fused_kernel<<<512, 512, 0, stream>>>(af, W1, b1, W2, b2, w3, b3, mw, out);
}

// Round 11
// 95.122 us; speedup vs baseline: 1.7913x; 1.7913x over previous
//
#include <hip/hip_runtime.h>
#include <hip/hip_bf16.h>

// CorrelationNetwork — single fused kernel for MI355X (gfx950), round 15.
// R14 post-mortem: fourth spill (WRITE 74MB scratch). The feasible region
// is now mapped by measurement:
//   - regs: >=64 persistent VGPRs across the tile loop spills under the
//     (512,4) 128-cap (R5/R10/R13/R14); ajr(32)+LDS-W2 body fits (R11/R12).
//   - LDS: R12 is at 80384B of the 81920B that keeps 2 blocks/CU; any
//     +2KB (part batching) halves occupancy (R9-style collapse); 3 blk/CU
//     needs <=53KB, impossible with W2s(32K)+AjF(33K).
// R12 = the joint-constraint optimum; both neighbors measured 15-75us
// worse. This round: LOCK IN R12 VERBATIM (proven 95.5us best) — the
// remaining in-kernel upside requires structures outside the measured
// feasible region, and the total is dominated by the ~58us harness
// invariant (42us workspace re-poison fill + restores + gaps).

typedef __bf16 bf16x8 __attribute__((ext_vector_type(8)));
typedef float f32x4 __attribute__((ext_vector_type(4)));

__device__ __forceinline__ unsigned rne16(float x) {
  unsigned u = __float_as_uint(x);
  u += 0x7fffu + ((u >> 16) & 1u);
  return u >> 16;
}
__device__ __forceinline__ __bf16 us_as_bf16(unsigned short s) {
  union { unsigned short s; __bf16 h; } cv; cv.s = s; return cv.h;
}

__global__ __launch_bounds__(512, 4) void fused_kernel(
    const float* __restrict__ af, const float* __restrict__ W1,
    const float* __restrict__ b1, const float* __restrict__ W2,
    const float* __restrict__ b2, const float* __restrict__ w3,
    const float* __restrict__ b3, const float* __restrict__ mw,
    float* __restrict__ out)
{
  // W2s (32 KB, tile phase) overlays flh/fll (18 KB, prepass staging)
  __shared__ __align__(16) unsigned short W2s[128 * 128];  // 32 KB
  __bf16* const flh = (__bf16*)W2s;                        // [64][72] hi
  __bf16* const fll = flh + 64 * 72;                       // [64][72] lo
  __shared__ __align__(16) float AjF[64 * 132];            // 33 KB, pad-132
  __shared__ __align__(16) float AiF[16 * 132];            // 8.25 KB
  __shared__ float b2s[128], w3s[128];
  __shared__ float part[2][2][128];                        // [tile&1][wm][row]

  const int tid  = threadIdx.x;
  const int lane = tid & 63;
  const int wave = tid >> 6;            // 0..7
  const int c = lane & 15, g = lane >> 4;
  const int wm = wave & 1;              // w2col half (64 cols)
  const int wn = wave >> 1;             // row quarter (32 rows)

  const int blk = blockIdx.x;
  const int b   = blk >> 2;             // 0..127
  const int iq  = blk & 3;              // i-quarter (8 i-pairs)
  const int ip0 = iq << 3;

  // ---- softmax of mixing weights (block 0, wave 0 only)
  if (blk == 0 && tid < 64) {
    float v = mw[tid];
    float m = v;
    for (int off = 32; off > 0; off >>= 1) m = fmaxf(m, __shfl_xor(m, off));
    float e = expf(v - m);
    float s = e;
    for (int off = 32; off > 0; off >>= 1) s += __shfl_xor(s, off);
    out[128 * 64 * 64 + tid] = e / s;
  }

  // ---- stage fl = af[b][0..63][0..63] split into bf16 hi/lo (pad-72 rows)
  {
    const float4* srcQ = (const float4*)(af + (b << 13));
#pragma unroll
    for (int p = 0; p < 2; ++p) {
      const int idx = (p << 9) + tid;            // 0..1023 float4s
      const int n = idx >> 4, e = idx & 15;
      const float4 v = srcQ[(n << 5) + e];
      const unsigned h0 = rne16(v.x), h1 = rne16(v.y),
                     h2 = rne16(v.z), h3 = rne16(v.w);
      const unsigned l0 = rne16(v.x - __uint_as_float(h0 << 16));
      const unsigned l1 = rne16(v.y - __uint_as_float(h1 << 16));
      const unsigned l2 = rne16(v.z - __uint_as_float(h2 << 16));
      const unsigned l3 = rne16(v.w - __uint_as_float(h3 << 16));
      uint2 ph; ph.x = h0 | (h1 << 16); ph.y = h2 | (h3 << 16);
      uint2 pl; pl.x = l0 | (l1 << 16); pl.y = l2 | (l3 << 16);
      *(uint2*)&flh[n * 72 + (e << 2)] = ph;
      *(uint2*)&fll[n * 72 + (e << 2)] = pl;
    }
    if (tid < 128) b2s[tid] = b2[tid];
    else if (tid < 256) w3s[tid - 128] = w3[tid - 128];
  }

  const float bias3 = b3[0];

  __syncthreads();                               // flh/fll, b2s/w3s ready

  // ---- MFMA prepass: wave w = htile (16 h-cols). D[m=h_loc][n=row] with
  // A = W1T frags (lane(c,g): h=w*16+c, f=base+g*8+e, hi/lo from global),
  // B = fl frags (lane(c,g): row=rt*16+c, f=base+g*8+e, hi/lo from LDS).
  // bf16x3: ah*bh + ah*bl + al*bh. Aj: rt 0..3 -> AjF; Ai: fl rows iq*16+c
  // -> AiF row c, C-init = b1.
  {
    const int w = wave;
    bf16x8 ajh[2], ajl[2], aih[2], ail[2];
#pragma unroll
    for (int kc = 0; kc < 2; ++kc) {
      const float* wpj = W1 + ((64 + (kc << 5) + (g << 3)) << 7) + (w << 4) + c;
      const float* wpi = W1 + (((kc << 5) + (g << 3)) << 7) + (w << 4) + c;
#pragma unroll
      for (int e = 0; e < 8; ++e) {
        const float vj = wpj[e << 7];
        const unsigned hj = rne16(vj);
        ajh[kc][e] = us_as_bf16((unsigned short)hj);
        ajl[kc][e] = us_as_bf16((unsigned short)rne16(vj - __uint_as_float(hj << 16)));
        const float vi = wpi[e << 7];
        const unsigned hi_ = rne16(vi);
        aih[kc][e] = us_as_bf16((unsigned short)hi_);
        ail[kc][e] = us_as_bf16((unsigned short)rne16(vi - __uint_as_float(hi_ << 16)));
      }
    }
#pragma unroll
    for (int rt = 0; rt < 4; ++rt) {
      const __bf16* bp = &flh[((rt << 4) + c) * 72 + (g << 3)];
      const __bf16* bq = &fll[((rt << 4) + c) * 72 + (g << 3)];
      f32x4 acc = {0.f, 0.f, 0.f, 0.f};
#pragma unroll
      for (int kc = 0; kc < 2; ++kc) {
        const bf16x8 bh = *(const bf16x8*)(bp + (kc << 5));
        const bf16x8 bl = *(const bf16x8*)(bq + (kc << 5));
        acc = __builtin_amdgcn_mfma_f32_16x16x32_bf16(ajh[kc], bh, acc, 0, 0, 0);
        acc = __builtin_amdgcn_mfma_f32_16x16x32_bf16(ajh[kc], bl, acc, 0, 0, 0);
        acc = __builtin_amdgcn_mfma_f32_16x16x32_bf16(ajl[kc], bh, acc, 0, 0, 0);
      }
      *(f32x4*)&AjF[((rt << 4) + c) * 132 + (w << 4) + (g << 2)] = acc;
    }
    {
      const __bf16* bp = &flh[((iq << 4) + c) * 72 + (g << 3)];
      const __bf16* bq = &fll[((iq << 4) + c) * 72 + (g << 3)];
      f32x4 acc = *(const f32x4*)(b1 + (w << 4) + (g << 2));
#pragma unroll
      for (int kc = 0; kc < 2; ++kc) {
        const bf16x8 bh = *(const bf16x8*)(bp + (kc << 5));
        const bf16x8 bl = *(const bf16x8*)(bq + (kc << 5));
        acc = __builtin_amdgcn_mfma_f32_16x16x32_bf16(aih[kc], bh, acc, 0, 0, 0);
        acc = __builtin_amdgcn_mfma_f32_16x16x32_bf16(aih[kc], bl, acc, 0, 0, 0);
        acc = __builtin_amdgcn_mfma_f32_16x16x32_bf16(ail[kc], bh, acc, 0, 0, 0);
      }
      *(f32x4*)&AiF[c * 132 + (w << 4) + (g << 2)] = acc;
    }
  }

  __syncthreads();                    // AjF/AiF ready; flh/fll dead

  // ---- W2 gather: f32 global -> RNE bf16 -> swizzled W2s (overlays flh).
  // Wave (wm, kt=wn); lane (c,g): m = wm*64+mt*16+c, k = kt*32+g*8+e,
  // chunk' = (kt*4+g)^c (R6-proven).
  {
    const int ktw = wn;
#pragma unroll
    for (int mt = 0; mt < 4; ++mt) {
      const int m = (wm << 6) + (mt << 4) + c;
      const float* wp = W2 + (((ktw << 5) + (g << 3)) << 7) + m;
      bf16x8 v;
#pragma unroll
      for (int e = 0; e < 8; ++e) {
        const float vv = wp[e << 7];
        v[e] = us_as_bf16((unsigned short)rne16(vv));
      }
      *(bf16x8*)&W2s[(m << 7) + ((((ktw << 2) + g) ^ c) << 3)] = v;
    }
  }

  // ---- tile-invariant Aj fragments -> registers (reads AjF, overlaps gather)
  f32x4 ajr[4][2][2];
#pragma unroll
  for (int kt = 0; kt < 4; ++kt)
#pragma unroll
    for (int tn = 0; tn < 2; ++tn) {
      const int j = ((wn << 5) + (tn << 4) + c) & 63;
      const float* ajb = &AjF[j * 132 + (g << 3) + (kt << 5)];
      ajr[kt][tn][0] = *(const f32x4*)(ajb);
      ajr[kt][tn][1] = *(const f32x4*)(ajb + 4);
    }

  __syncthreads();                               // W2s ready

  const int i_sel = wn >> 1;                     // row>=64 -> second i of pair

  for (int t = 0; t < 8; ++t) {
    const float* aib = &AiF[((t << 1) + i_sel) * 132 + (g << 3)];

    f32x4 acc[4][2];
#pragma unroll
    for (int mt = 0; mt < 4; ++mt) {
      const f32x4 bv = *(const f32x4*)&b2s[(wm << 6) + (mt << 4) + (g << 2)];
      acc[mt][0] = bv;
      acc[mt][1] = bv;
    }

#pragma unroll
    for (int kt = 0; kt < 4; ++kt) {
      const int es = ((kt << 2) + g) ^ c;
      bf16x8 wv[4];
#pragma unroll
      for (int mt = 0; mt < 4; ++mt)
        wv[mt] = *(const bf16x8*)&W2s[(((wm << 6) + (mt << 4) + c) << 7) + (es << 3)];

      const f32x4 a0 = *(const f32x4*)(aib + (kt << 5));
      const f32x4 a1 = *(const f32x4*)(aib + (kt << 5) + 4);
      bf16x8 hv[2];
#pragma unroll
      for (int tn = 0; tn < 2; ++tn) {
        const f32x4 h0  = a0 + ajr[kt][tn][0];
        const f32x4 h1v = a1 + ajr[kt][tn][1];
#pragma unroll
        for (int e = 0; e < 4; ++e) {
          hv[tn][e]     = (__bf16)fmaxf(h0[e], 0.f);
          hv[tn][e + 4] = (__bf16)fmaxf(h1v[e], 0.f);
        }
      }
#pragma unroll
      for (int mt = 0; mt < 4; ++mt)
#pragma unroll
        for (int tn = 0; tn < 2; ++tn)
          acc[mt][tn] = __builtin_amdgcn_mfma_f32_16x16x32_bf16(
              wv[mt], hv[tn], acc[mt][tn], 0, 0, 0);
    }

    float s0 = 0.f, s1 = 0.f;
#pragma unroll
    for (int mt = 0; mt < 4; ++mt) {
      const f32x4 wv3 = *(const f32x4*)&w3s[(wm << 6) + (mt << 4) + (g << 2)];
#pragma unroll
      for (int p = 0; p < 4; ++p) {
        s0 = fmaf(fmaxf(acc[mt][0][p], 0.f), wv3[p], s0);
        s1 = fmaf(fmaxf(acc[mt][1][p], 0.f), wv3[p], s1);
      }
    }
    s0 += __shfl_xor(s0, 16);
    s0 += __shfl_xor(s0, 32);
    s1 += __shfl_xor(s1, 16);
    s1 += __shfl_xor(s1, 32);

    const int pb = t & 1;
    if (g == 0) {                                // 16 lanes, conflict-free
      part[pb][wm][(wn << 5) + c]      = s0;
      part[pb][wm][(wn << 5) + 16 + c] = s1;
    }

    __syncthreads();                             // one barrier per tile

    if (tid < 128) {
      const float v = part[pb][0][tid] + part[pb][1][tid] + bias3;
      out[(b << 12) + ((ip0 + t) << 7) + tid] = 1.f / (1.f + __expf(-v));
    }
  }
}

extern "C" void kernel_launch(void* const* d_in, const int* in_sizes, int n_in,
                              void* d_out, int out_size, void* d_ws,
                              size_t ws_size, hipStream_t stream)
{
  const float* af = (const float*)d_in[0];   // (128,64,128)
  const float* W1 = (const float*)d_in[1];   // (128,128)
  const float* b1 = (const float*)d_in[2];   // (128,)
  const float* W2 = (const float*)d_in[3];   // (128,128)
  const float* b2 = (const float*)d_in[4];   // (128,)
  const float* w3 = (const float*)d_in[5];   // (128,)
  const float* b3 = (const float*)d_in[6];   // (1,)
  const float* mw = (const float*)d_in[7];   // (64,)
  float* out = (float*)d_out;                // 524288 corr + 64 weights

  (void)d_ws; (void)ws_size;
  // one kernel: 512 blocks (2/CU), block = (b, i-quarter), 8 tiles each
  fused_kernel<<<512, 512, 0, stream>>>(af, W1, b1, W2, b2, w3, b3, mw, out);
}